// Round 2
// baseline (3892.602 us; speedup 1.0000x reference)
//
#include <hip/hip_runtime.h>
#include <hip/hip_bf16.h>
#include <math.h>

#define B_ 16
#define S_ 2048
#define DM_ 64
#define HD_ 1024

typedef short short8 __attribute__((ext_vector_type(8)));
typedef float floatx4 __attribute__((ext_vector_type(4)));

static __device__ inline unsigned short f2bf(float f) {
    __hip_bfloat16 h = __float2bfloat16(f);
    return *reinterpret_cast<unsigned short*>(&h);
}

// ---------------------------------------------------------------------------
// K1: fused QKV projection.  x[32768x64] (fp32) @ W[64x3072] (fp32).
// q,k written bf16 row-major [B*S][1024]; v written transposed vt[b][1024][2048].
// One thread = one output column (W column in 64 VGPRs), 128 rows per block.
// ---------------------------------------------------------------------------
__global__ __launch_bounds__(256, 2) void k_proj(
        const float* __restrict__ x, const float* __restrict__ W,
        unsigned short* __restrict__ q, unsigned short* __restrict__ k,
        unsigned short* __restrict__ vt) {
    __shared__ __align__(16) unsigned short vbuf[256][136]; // pad: 272B rows, 16B aligned

    const int tid  = threadIdx.x;
    const int bx   = blockIdx.x;       // 0..11 column block (256 cols each)
    const int by   = blockIdx.y;       // 0..255 row block (128 rows each)
    const int col0 = bx * 256;
    const int c    = col0 + tid;       // 0..3071
    const int r0   = by * 128;

    float wreg[64];
#pragma unroll
    for (int d = 0; d < 64; ++d) wreg[d] = W[d * 3072 + c];

    const bool isv = (bx >= 8);
    unsigned short* outbase = (bx < 4) ? q : k;
    const int cc = (bx < 4) ? c : (c - 1024);   // only meaningful for q/k blocks

    for (int r = 0; r < 128; ++r) {
        const int row = r0 + r;
        const floatx4* xr = (const floatx4*)(x + (size_t)row * DM_);
        float a0 = 0.f, a1 = 0.f, a2 = 0.f, a3 = 0.f;
#pragma unroll
        for (int j = 0; j < 16; ++j) {
            floatx4 xv = xr[j];
            a0 = fmaf(xv.x, wreg[4 * j + 0], a0);
            a1 = fmaf(xv.y, wreg[4 * j + 1], a1);
            a2 = fmaf(xv.z, wreg[4 * j + 2], a2);
            a3 = fmaf(xv.w, wreg[4 * j + 3], a3);
        }
        const unsigned short u = f2bf((a0 + a1) + (a2 + a3));
        if (isv) vbuf[tid][r] = u;
        else     outbase[(size_t)row * HD_ + cc] = u;
    }

    if (isv) {
        __syncthreads();
        const int d  = c - 2048;            // 0..1023
        const int b  = r0 >> 11;            // row block never straddles a batch
        const int s0 = r0 & 2047;
        unsigned short* dst = vt + ((size_t)b * HD_ + d) * S_ + s0;
        const short8* src = (const short8*)(&vbuf[tid][0]);
#pragma unroll
        for (int i = 0; i < 16; ++i) ((short8*)dst)[i] = src[i];
    }
}

// ---------------------------------------------------------------------------
// K2: flash-style attention with online softmax, bf16 MFMA 16x16x32.
// Workgroup = 32 query rows, key tiles of 64, 4 waves.
//   Phase A: wave w computes full-D logits for keys [kt+16w, kt+16w+16)
//   Phase B: online softmax stats (8 lanes/row shfl reductions), P -> bf16 LDS
//   Phase C: wave w accumulates O slice [32 x 256] (d-slice 256w..256w+255)
// Masking faithful to ref: s*=0.25; if (j<i || s==0) s=-9e15; softmax.
// ---------------------------------------------------------------------------
#define MQ_ 32
#define NK_ 64

__global__ __launch_bounds__(256, 2) void k_attn(
        const unsigned short* __restrict__ qg,
        const unsigned short* __restrict__ kg,
        const unsigned short* __restrict__ vtg,
        float* __restrict__ out) {
    __shared__ __align__(16) unsigned short qs[32 * 1032];  // Q tile, pad +8
    __shared__ float lg[32 * 66];                           // logits, pad +2
    __shared__ __align__(16) unsigned short ps[32 * 72];    // P bf16, pad +8
    __shared__ float m_s[32], l_s[32], al_s[32];

    const int tid  = threadIdx.x;
    const int wv   = tid >> 6;
    const int lane = tid & 63;
    const int quad = lane >> 4;
    const int l16  = lane & 15;

    const int bb = blockIdx.x & 15;   // batch
    const int qt = blockIdx.x >> 4;   // 0..63 ; qt=0 (most work) dispatches first
    const int q0 = qt * MQ_;

    // stage Q tile -> LDS  (each of 8 threads/row covers 128 shorts = 16 x short8)
    {
        const int row = tid >> 3;
        const int cb  = (tid & 7) * 128;
        const unsigned short* src = qg + ((size_t)(bb * S_ + q0 + row)) * HD_ + cb;
        unsigned short* dst = qs + row * 1032 + cb;
#pragma unroll
        for (int i = 0; i < 16; ++i) ((short8*)dst)[i] = ((const short8*)src)[i];
    }
    if (tid < 32) { m_s[tid] = -INFINITY; l_s[tid] = 0.f; }
    __syncthreads();

    floatx4 o[2][16];
    const floatx4 z4 = {0.f, 0.f, 0.f, 0.f};
#pragma unroll
    for (int rt = 0; rt < 2; ++rt)
#pragma unroll
        for (int ct = 0; ct < 16; ++ct) o[rt][ct] = z4;

    const int kt0 = (q0 / NK_) * NK_;
    const unsigned short* kbase = kg  + ((size_t)bb * S_) * HD_;
    const unsigned short* vbase = vtg + ((size_t)bb * HD_) * S_;

    for (int kt = kt0; kt < S_; kt += NK_) {
        // ---- Phase A: QK^T ----
        const int keyl = wv * 16 + l16;        // local key in [0,64)
        const int key  = kt + keyl;            // global key (within batch)
        floatx4 sc0 = z4, sc1 = z4;
        const unsigned short* kp = kbase + (size_t)key * HD_ + quad * 8;
#pragma unroll 4
        for (int ks = 0; ks < 32; ++ks) {
            short8 kf  = *((const short8*)(kp + ks * 32));
            short8 qf0 = *((const short8*)(qs + l16 * 1032 + ks * 32 + quad * 8));
            short8 qf1 = *((const short8*)(qs + (16 + l16) * 1032 + ks * 32 + quad * 8));
            sc0 = __builtin_amdgcn_mfma_f32_16x16x32_bf16(qf0, kf, sc0, 0, 0, 0);
            sc1 = __builtin_amdgcn_mfma_f32_16x16x32_bf16(qf1, kf, sc1, 0, 0, 0);
        }
#pragma unroll
        for (int rt = 0; rt < 2; ++rt) {
#pragma unroll
            for (int rg = 0; rg < 4; ++rg) {
                const int row = rt * 16 + quad * 4 + rg;
                float v = (rt == 0 ? sc0[rg] : sc1[rg]) * 0.25f;
                const int gi = q0 + row;
                if (key < gi || v == 0.0f) v = -9.0e15f;  // faithful triu + ==0 mask
                lg[row * 66 + keyl] = v;
            }
        }
        __syncthreads();

        // ---- Phase B: online softmax ----
        {
            const int row = tid >> 3;
            const int j   = tid & 7;
            float vals[8];
            float tmax = -INFINITY;
#pragma unroll
            for (int i = 0; i < 8; ++i) {
                vals[i] = lg[row * 66 + j + 8 * i];
                tmax = fmaxf(tmax, vals[i]);
            }
            tmax = fmaxf(tmax, __shfl_xor(tmax, 1, 8));
            tmax = fmaxf(tmax, __shfl_xor(tmax, 2, 8));
            tmax = fmaxf(tmax, __shfl_xor(tmax, 4, 8));
            const float mold = m_s[row];
            const float mnew = fmaxf(mold, tmax);
            float tsum = 0.f;
#pragma unroll
            for (int i = 0; i < 8; ++i) {
                const float p = __expf(vals[i] - mnew);   // masked -> exp(-huge)=0
                tsum += p;
                ps[row * 72 + j + 8 * i] = f2bf(p);
            }
            tsum += __shfl_xor(tsum, 1, 8);
            tsum += __shfl_xor(tsum, 2, 8);
            tsum += __shfl_xor(tsum, 4, 8);
            if (j == 0) {
                const float al = __expf(mold - mnew);
                al_s[row] = al;
                m_s[row]  = mnew;
                l_s[row]  = l_s[row] * al + tsum;
            }
        }
        __syncthreads();

        // ---- Phase C: rescale O, then O += P @ V ----
#pragma unroll
        for (int rt = 0; rt < 2; ++rt) {
#pragma unroll
            for (int rg = 0; rg < 4; ++rg) {
                const float a = al_s[rt * 16 + quad * 4 + rg];
#pragma unroll
                for (int ct = 0; ct < 16; ++ct) o[rt][ct][rg] *= a;
            }
        }
#pragma unroll
        for (int ks = 0; ks < 2; ++ks) {
            short8 pf0 = *((const short8*)(ps + l16 * 72 + ks * 32 + quad * 8));
            short8 pf1 = *((const short8*)(ps + (16 + l16) * 72 + ks * 32 + quad * 8));
            const unsigned short* vp =
                vbase + (size_t)(wv * 256 + l16) * S_ + kt + ks * 32 + quad * 8;
#pragma unroll 4
            for (int ct = 0; ct < 16; ++ct) {
                short8 vf = *((const short8*)(vp + (size_t)ct * 16 * S_));
                o[0][ct] = __builtin_amdgcn_mfma_f32_16x16x32_bf16(pf0, vf, o[0][ct], 0, 0, 0);
                o[1][ct] = __builtin_amdgcn_mfma_f32_16x16x32_bf16(pf1, vf, o[1][ct], 0, 0, 0);
            }
        }
        __syncthreads();
    }

    // ---- epilogue: O / l ----
#pragma unroll
    for (int rt = 0; rt < 2; ++rt) {
#pragma unroll
        for (int rg = 0; rg < 4; ++rg) {
            const int row = rt * 16 + quad * 4 + rg;
            const float linv = 1.0f / l_s[row];
            float* op = out + ((size_t)(bb * S_ + q0 + row)) * HD_ + wv * 256 + l16;
#pragma unroll
            for (int ct = 0; ct < 16; ++ct) op[ct * 16] = o[rt][ct][rg] * linv;
        }
    }
}

extern "C" void kernel_launch(void* const* d_in, const int* in_sizes, int n_in,
                              void* d_out, int out_size, void* d_ws, size_t ws_size,
                              hipStream_t stream) {
    const float* x = (const float*)d_in[0];
    const float* W = (const float*)d_in[1];
    float* out = (float*)d_out;

    const size_t n = (size_t)B_ * S_ * HD_;     // 33,554,432 elements
    unsigned short* q  = (unsigned short*)d_ws; // bf16 q  [B*S][1024]
    unsigned short* k  = q + n;                 // bf16 k  [B*S][1024]
    unsigned short* vt = k + n;                 // bf16 vt [B][1024][2048]
    // total ws use: 3*n*2 = 192 MiB

    k_proj<<<dim3(12, 256), 256, 0, stream>>>(x, W, q, k, vt);
    k_attn<<<dim3(1024), 256, 0, stream>>>(q, k, vt, out);
}

// Round 3
// 2150.792 us; speedup vs baseline: 1.8098x; 1.8098x over previous
//
#include <hip/hip_runtime.h>
#include <hip/hip_bf16.h>
#include <math.h>

#define B_ 16
#define S_ 2048
#define DM_ 64
#define HD_ 1024

typedef short short8 __attribute__((ext_vector_type(8)));
typedef float floatx4 __attribute__((ext_vector_type(4)));

static __device__ inline unsigned short f2bf(float f) {
    __hip_bfloat16 h = __float2bfloat16(f);
    return *reinterpret_cast<unsigned short*>(&h);
}

// ---------------------------------------------------------------------------
// K1: fused QKV projection.  x[32768x64] (fp32) @ W[64x3072] (fp32).
// q,k written bf16 row-major [B*S][1024]; v written transposed vt[b][1024][2048].
// One thread = one output column (W column in 64 VGPRs), 128 rows per block.
// ---------------------------------------------------------------------------
__global__ __launch_bounds__(256, 2) void k_proj(
        const float* __restrict__ x, const float* __restrict__ W,
        unsigned short* __restrict__ q, unsigned short* __restrict__ k,
        unsigned short* __restrict__ vt) {
    __shared__ __align__(16) unsigned short vbuf[256][136]; // pad: 272B rows, 16B aligned

    const int tid  = threadIdx.x;
    const int bx   = blockIdx.x;       // 0..11 column block (256 cols each)
    const int by   = blockIdx.y;       // 0..255 row block (128 rows each)
    const int col0 = bx * 256;
    const int c    = col0 + tid;       // 0..3071
    const int r0   = by * 128;

    float wreg[64];
#pragma unroll
    for (int d = 0; d < 64; ++d) wreg[d] = W[d * 3072 + c];

    const bool isv = (bx >= 8);
    unsigned short* outbase = (bx < 4) ? q : k;
    const int cc = (bx < 4) ? c : (c - 1024);   // only meaningful for q/k blocks

    for (int r = 0; r < 128; ++r) {
        const int row = r0 + r;
        const floatx4* xr = (const floatx4*)(x + (size_t)row * DM_);
        float a0 = 0.f, a1 = 0.f, a2 = 0.f, a3 = 0.f;
#pragma unroll
        for (int j = 0; j < 16; ++j) {
            floatx4 xv = xr[j];
            a0 = fmaf(xv.x, wreg[4 * j + 0], a0);
            a1 = fmaf(xv.y, wreg[4 * j + 1], a1);
            a2 = fmaf(xv.z, wreg[4 * j + 2], a2);
            a3 = fmaf(xv.w, wreg[4 * j + 3], a3);
        }
        const unsigned short u = f2bf((a0 + a1) + (a2 + a3));
        if (isv) vbuf[tid][r] = u;
        else     outbase[(size_t)row * HD_ + cc] = u;
    }

    if (isv) {
        __syncthreads();
        const int d  = c - 2048;            // 0..1023
        const int b  = r0 >> 11;            // row block never straddles a batch
        const int s0 = r0 & 2047;
        unsigned short* dst = vt + ((size_t)b * HD_ + d) * S_ + s0;
        const short8* src = (const short8*)(&vbuf[tid][0]);
#pragma unroll
        for (int i = 0; i < 16; ++i) ((short8*)dst)[i] = src[i];
    }
}

// ---------------------------------------------------------------------------
// K2: flash-style attention with online softmax, bf16 MFMA 16x16x32.
// Workgroup = 32 query rows, key tiles of 64, 4 waves.
//   Phase A: wave w computes full-D logits for keys [kt+16w, kt+16w+16)
//   Phase B: online softmax stats (8 lanes/row shfl reductions), P -> bf16 LDS
//   Phase C: wave w accumulates O slice [32 x 256] (d-slice 256w..256w+255)
// Masking faithful to ref: s*=0.25; if (j<i || s==0) s=-9e15; softmax.
//
// NOTE: every loop touching o[][] MUST be fully unrolled — a partial unroll
// makes the index dynamic and demotes the 128-reg accumulator to scratch
// (R2: 6.7 GB of scratch writes per dispatch, 10x slowdown).
// ---------------------------------------------------------------------------
#define MQ_ 32
#define NK_ 64

__global__ __launch_bounds__(256, 2) void k_attn(
        const unsigned short* __restrict__ qg,
        const unsigned short* __restrict__ kg,
        const unsigned short* __restrict__ vtg,
        float* __restrict__ out) {
    __shared__ __align__(16) unsigned short qs[32 * 1032];  // Q tile, pad +8
    __shared__ float lg[32 * 66];                           // logits, pad +2
    __shared__ __align__(16) unsigned short ps[32 * 72];    // P bf16, pad +8
    __shared__ float m_s[32], l_s[32], al_s[32];

    const int tid  = threadIdx.x;
    const int wv   = tid >> 6;
    const int lane = tid & 63;
    const int quad = lane >> 4;
    const int l16  = lane & 15;

    // batch-major swizzle: 64 same-batch blocks are consecutive in dispatch
    // order, so co-resident blocks share K/V working set in L2/L3 (R2 showed
    // 5 GB FETCH vs 340 MB compulsory with qt-major order).
    const int bb = blockIdx.x >> 6;   // batch
    const int qt = blockIdx.x & 63;   // 0..63 ; qt=0 (most work) dispatches first
    const int q0 = qt * MQ_;

    // stage Q tile -> LDS  (each of 8 threads/row covers 128 shorts = 16 x short8)
    {
        const int row = tid >> 3;
        const int cb  = (tid & 7) * 128;
        const unsigned short* src = qg + ((size_t)(bb * S_ + q0 + row)) * HD_ + cb;
        unsigned short* dst = qs + row * 1032 + cb;
#pragma unroll
        for (int i = 0; i < 16; ++i) ((short8*)dst)[i] = ((const short8*)src)[i];
    }
    if (tid < 32) { m_s[tid] = -INFINITY; l_s[tid] = 0.f; }
    __syncthreads();

    floatx4 o[2][16];
    const floatx4 z4 = {0.f, 0.f, 0.f, 0.f};
#pragma unroll
    for (int rt = 0; rt < 2; ++rt)
#pragma unroll
        for (int ct = 0; ct < 16; ++ct) o[rt][ct] = z4;

    const int kt0 = (q0 / NK_) * NK_;
    const unsigned short* kbase = kg  + ((size_t)bb * S_) * HD_;
    const unsigned short* vbase = vtg + ((size_t)bb * HD_) * S_;

    for (int kt = kt0; kt < S_; kt += NK_) {
        // ---- Phase A: QK^T ----
        const int keyl = wv * 16 + l16;        // local key in [0,64)
        const int key  = kt + keyl;            // global key (within batch)
        floatx4 sc0 = z4, sc1 = z4;
        const unsigned short* kp = kbase + (size_t)key * HD_ + quad * 8;
#pragma unroll 4
        for (int ks = 0; ks < 32; ++ks) {
            short8 kf  = *((const short8*)(kp + ks * 32));
            short8 qf0 = *((const short8*)(qs + l16 * 1032 + ks * 32 + quad * 8));
            short8 qf1 = *((const short8*)(qs + (16 + l16) * 1032 + ks * 32 + quad * 8));
            sc0 = __builtin_amdgcn_mfma_f32_16x16x32_bf16(qf0, kf, sc0, 0, 0, 0);
            sc1 = __builtin_amdgcn_mfma_f32_16x16x32_bf16(qf1, kf, sc1, 0, 0, 0);
        }
#pragma unroll
        for (int rt = 0; rt < 2; ++rt) {
#pragma unroll
            for (int rg = 0; rg < 4; ++rg) {
                const int row = rt * 16 + quad * 4 + rg;
                float v = (rt == 0 ? sc0[rg] : sc1[rg]) * 0.25f;
                const int gi = q0 + row;
                if (key < gi || v == 0.0f) v = -9.0e15f;  // faithful triu + ==0 mask
                lg[row * 66 + keyl] = v;
            }
        }
        __syncthreads();

        // ---- Phase B: online softmax ----
        {
            const int row = tid >> 3;
            const int j   = tid & 7;
            float vals[8];
            float tmax = -INFINITY;
#pragma unroll
            for (int i = 0; i < 8; ++i) {
                vals[i] = lg[row * 66 + j + 8 * i];
                tmax = fmaxf(tmax, vals[i]);
            }
            tmax = fmaxf(tmax, __shfl_xor(tmax, 1, 8));
            tmax = fmaxf(tmax, __shfl_xor(tmax, 2, 8));
            tmax = fmaxf(tmax, __shfl_xor(tmax, 4, 8));
            const float mold = m_s[row];
            const float mnew = fmaxf(mold, tmax);
            float tsum = 0.f;
#pragma unroll
            for (int i = 0; i < 8; ++i) {
                const float p = __expf(vals[i] - mnew);   // masked -> exp(-huge)=0
                tsum += p;
                ps[row * 72 + j + 8 * i] = f2bf(p);
            }
            tsum += __shfl_xor(tsum, 1, 8);
            tsum += __shfl_xor(tsum, 2, 8);
            tsum += __shfl_xor(tsum, 4, 8);
            if (j == 0) {
                const float al = __expf(mold - mnew);
                al_s[row] = al;
                m_s[row]  = mnew;
                l_s[row]  = l_s[row] * al + tsum;
            }
        }
        __syncthreads();

        // ---- Phase C: rescale O, then O += P @ V ----
#pragma unroll
        for (int rt = 0; rt < 2; ++rt) {
#pragma unroll
            for (int rg = 0; rg < 4; ++rg) {
                const float a = al_s[rt * 16 + quad * 4 + rg];
#pragma unroll
                for (int ct = 0; ct < 16; ++ct) o[rt][ct][rg] *= a;
            }
        }
#pragma unroll
        for (int ks = 0; ks < 2; ++ks) {
            short8 pf0 = *((const short8*)(ps + l16 * 72 + ks * 32 + quad * 8));
            short8 pf1 = *((const short8*)(ps + (16 + l16) * 72 + ks * 32 + quad * 8));
            const unsigned short* vp =
                vbase + (size_t)(wv * 256 + l16) * S_ + kt + ks * 32 + quad * 8;
#pragma unroll
            for (int ct = 0; ct < 16; ++ct) {   // FULL unroll: o must stay in regs
                short8 vf = *((const short8*)(vp + (size_t)ct * 16 * S_));
                o[0][ct] = __builtin_amdgcn_mfma_f32_16x16x32_bf16(pf0, vf, o[0][ct], 0, 0, 0);
                o[1][ct] = __builtin_amdgcn_mfma_f32_16x16x32_bf16(pf1, vf, o[1][ct], 0, 0, 0);
            }
        }
        __syncthreads();
    }

    // ---- epilogue: O / l ----
#pragma unroll
    for (int rt = 0; rt < 2; ++rt) {
#pragma unroll
        for (int rg = 0; rg < 4; ++rg) {
            const int row = rt * 16 + quad * 4 + rg;
            const float linv = 1.0f / l_s[row];
            float* op = out + ((size_t)(bb * S_ + q0 + row)) * HD_ + wv * 256 + l16;
#pragma unroll
            for (int ct = 0; ct < 16; ++ct) op[ct * 16] = o[rt][ct][rg] * linv;
        }
    }
}

extern "C" void kernel_launch(void* const* d_in, const int* in_sizes, int n_in,
                              void* d_out, int out_size, void* d_ws, size_t ws_size,
                              hipStream_t stream) {
    const float* x = (const float*)d_in[0];
    const float* W = (const float*)d_in[1];
    float* out = (float*)d_out;

    const size_t n = (size_t)B_ * S_ * HD_;     // 33,554,432 elements
    unsigned short* q  = (unsigned short*)d_ws; // bf16 q  [B*S][1024]
    unsigned short* k  = q + n;                 // bf16 k  [B*S][1024]
    unsigned short* vt = k + n;                 // bf16 vt [B][1024][2048]
    // total ws use: 3*n*2 = 192 MiB

    k_proj<<<dim3(12, 256), 256, 0, stream>>>(x, W, q, k, vt);
    k_attn<<<dim3(1024), 256, 0, stream>>>(q, k, vt, out);
}

// Round 4
// 388.294 us; speedup vs baseline: 10.0249x; 5.5391x over previous
//
#include <hip/hip_runtime.h>
#include <hip/hip_bf16.h>
#include <math.h>

#define B_ 16
#define S_ 2048
#define DM_ 64
#define HD_ 1024

typedef float floatx4 __attribute__((ext_vector_type(4)));

// ---------------------------------------------------------------------------
// Algebraic refactor:
//   logits = (x Wq)(x Wk)^T = x M x^T,  M = Wq Wk^T (64x64)
//   out    = softmax(mask(logits/4)) @ (x Wv) = (P @ x) @ Wv
// so the softmax loop only ever touches 64-dim vectors. FLOPs 150 GF -> 13 GF,
// K/V tile traffic 256 KB -> 16 KB (x only; 512 KB/batch, L2-resident).
// Entire attention path is fp32 (no bf16): absmax headroom vs 0.139 threshold.
// ---------------------------------------------------------------------------

// K1: M[d][e] = sum_f W[d][f] * W[e][1024+f]   (Wq row d . Wk row e)
__global__ void k_M(const float* __restrict__ W, float* __restrict__ M) {
    const int d = blockIdx.x;     // 0..63
    const int e = threadIdx.x;    // 0..63
    const floatx4* wq = (const floatx4*)(W + (size_t)d * 3072);
    const floatx4* wk = (const floatx4*)(W + (size_t)e * 3072 + 1024);
    floatx4 a = {0.f, 0.f, 0.f, 0.f};
    for (int j = 0; j < 256; ++j) {
        floatx4 qv = wq[j], kv = wk[j];
        a.x = fmaf(qv.x, kv.x, a.x);
        a.y = fmaf(qv.y, kv.y, a.y);
        a.z = fmaf(qv.z, kv.z, a.z);
        a.w = fmaf(qv.w, kv.w, a.w);
    }
    M[d * 64 + e] = (a.x + a.y) + (a.z + a.w);
}

// K2: y = x @ M   [32768 x 64] @ [64 x 64], fp32.
// Block: 128 rows; thread: col c = tid&63, row-group g = tid>>6 (32 rows each).
__global__ __launch_bounds__(256, 2) void k_y(
        const float* __restrict__ x, const float* __restrict__ M,
        float* __restrict__ y) {
    __shared__ __align__(16) float xs[128 * 64];   // broadcast reads: no pad needed
    const int tid = threadIdx.x;
    const int c   = tid & 63;
    const int g   = tid >> 6;
    const int r0  = blockIdx.x * 128;

    // stage 128 x-rows (flat coalesced copy)
    {
        const floatx4* src = (const floatx4*)(x + (size_t)r0 * 64);
        floatx4* dst = (floatx4*)xs;
#pragma unroll
        for (int i = 0; i < 8; ++i) dst[tid * 8 + i] = src[tid * 8 + i];
    }
    float mreg[64];
#pragma unroll
    for (int d = 0; d < 64; ++d) mreg[d] = M[d * 64 + c];
    __syncthreads();

    for (int r = 0; r < 32; ++r) {
        const int row = g * 32 + r;
        const floatx4* xr = (const floatx4*)(xs + row * 64);
        float a0 = 0.f, a1 = 0.f, a2 = 0.f, a3 = 0.f;
#pragma unroll
        for (int j = 0; j < 16; ++j) {
            floatx4 xv = xr[j];
            a0 = fmaf(xv.x, mreg[4 * j + 0], a0);
            a1 = fmaf(xv.y, mreg[4 * j + 1], a1);
            a2 = fmaf(xv.z, mreg[4 * j + 2], a2);
            a3 = fmaf(xv.w, mreg[4 * j + 3], a3);
        }
        y[(size_t)(r0 + row) * 64 + c] = (a0 + a1) + (a2 + a3);
    }
}

// K3: flash attention in fp32, 64-dim features.
// Block = 64 query rows of one batch; key tiles of 64.
// Thread grid 16x16: qi=tid>>4 owns rows qi*4..+3, ki=tid&15 owns keys ki*4..+3.
// Same-qi threads are 16 contiguous lanes -> shfl_xor(1,2,4,8) row reductions.
// Softmax state (m,l) lives in registers, replicated across the 16-lane group
// (butterfly reductions are bitwise-identical on all lanes).
// Un (=P@X normalized) written to ws; final @Wv is k_out.
// NOTE: keep all loops over r/c (register tiles) fully unrolled (R2 lesson:
// dynamic index -> scratch spill, 6.7 GB of write traffic).
__global__ __launch_bounds__(256, 2) void k_attn2(
        const float* __restrict__ xg, const float* __restrict__ yg,
        float* __restrict__ Un) {
    __shared__ __align__(16) float y_t[64 * 68];   // y_t[d][q_local]
    __shared__ __align__(16) float x_t[64 * 68];   // x_t[d][key_local]
    __shared__ __align__(16) float x_r[64 * 68];   // x_r[key_local][d]
    __shared__ __align__(16) float P_t[64 * 68];   // P_t[key_local][q_local]

    const int tid = threadIdx.x;
    const int qi  = tid >> 4;      // 0..15
    const int ki  = tid & 15;      // 0..15

    // Load-balance: pair q-tile qt with 31-qt (work 32-qt + 1+qt = 33 const).
    // half 0 (bids 0..255) = heavy qt 0..15, half 1 = light qt 31..16.
    const int half = blockIdx.x >> 8;
    const int idx  = blockIdx.x & 255;
    const int bb   = idx & 15;
    const int qtl  = idx >> 4;
    const int qt   = half ? (31 - qtl) : qtl;
    const int q0   = qt * 64;

    // stage y tile -> y_t[d][q]  (once per block)
    {
        const int qrow = tid >> 2, part = tid & 3;
        const floatx4* src =
            (const floatx4*)(yg + ((size_t)bb * S_ + q0 + qrow) * 64 + part * 16);
#pragma unroll
        for (int j = 0; j < 4; ++j) {
            floatx4 v = src[j];
#pragma unroll
            for (int l = 0; l < 4; ++l)
                y_t[(part * 16 + j * 4 + l) * 68 + qrow] = v[l];
        }
    }

    float U[4][4], m[4], l[4];
#pragma unroll
    for (int r = 0; r < 4; ++r) {
        m[r] = -INFINITY; l[r] = 0.f;
#pragma unroll
        for (int c = 0; c < 4; ++c) U[r][c] = 0.f;
    }

    const float* xb = xg + (size_t)bb * S_ * 64;

    for (int kt = q0; kt < S_; kt += 64) {
        __syncthreads();   // prev tile readers done with x_r/x_t/P_t
        // stage x tile -> x_r (row) and x_t (transposed)
        {
            const int key = tid >> 2, part = tid & 3;
            const floatx4* src = (const floatx4*)(xb + (size_t)(kt + key) * 64 + part * 16);
#pragma unroll
            for (int j = 0; j < 4; ++j) {
                floatx4 v = src[j];
                *(floatx4*)(x_r + key * 68 + part * 16 + j * 4) = v;
#pragma unroll
                for (int l = 0; l < 4; ++l)
                    x_t[(part * 16 + j * 4 + l) * 68 + key] = v[l];
            }
        }
        __syncthreads();

        // ---- QK: s[4][4] = y_tile(rows) . x_tile(keys), K=64 ----
        float s[4][4];
#pragma unroll
        for (int r = 0; r < 4; ++r)
#pragma unroll
            for (int c = 0; c < 4; ++c) s[r][c] = 0.f;
#pragma unroll 8
        for (int kk = 0; kk < 64; ++kk) {
            floatx4 a = *(const floatx4*)(y_t + kk * 68 + qi * 4);
            floatx4 b = *(const floatx4*)(x_t + kk * 68 + ki * 4);
#pragma unroll
            for (int r = 0; r < 4; ++r)
#pragma unroll
                for (int c = 0; c < 4; ++c) s[r][c] = fmaf(a[r], b[c], s[r][c]);
        }

        // ---- scale + faithful mask + online softmax ----
        float p[4][4], alpha[4];
#pragma unroll
        for (int r = 0; r < 4; ++r) {
            const int ig = q0 + qi * 4 + r;
            float rmax = -INFINITY;
#pragma unroll
            for (int c = 0; c < 4; ++c) {
                const int jg = kt + ki * 4 + c;
                float v = s[r][c] * 0.25f;
                if (jg < ig || v == 0.0f) v = -9.0e15f;  // triu + (==0 -> -9e15)
                s[r][c] = v;
                rmax = fmaxf(rmax, v);
            }
            rmax = fmaxf(rmax, __shfl_xor(rmax, 1));
            rmax = fmaxf(rmax, __shfl_xor(rmax, 2));
            rmax = fmaxf(rmax, __shfl_xor(rmax, 4));
            rmax = fmaxf(rmax, __shfl_xor(rmax, 8));
            const float mnew = fmaxf(m[r], rmax);
            alpha[r] = __expf(m[r] - mnew);            // first tile: exp(-inf)=0
            float psum = 0.f;
#pragma unroll
            for (int c = 0; c < 4; ++c) {
                const float pv = __expf(s[r][c] - mnew);
                p[r][c] = pv;
                psum += pv;
            }
            psum += __shfl_xor(psum, 1);
            psum += __shfl_xor(psum, 2);
            psum += __shfl_xor(psum, 4);
            psum += __shfl_xor(psum, 8);
            m[r] = mnew;
            l[r] = l[r] * alpha[r] + psum;
        }

        // P -> LDS transposed: P_t[key][q]
#pragma unroll
        for (int r = 0; r < 4; ++r)
#pragma unroll
            for (int c = 0; c < 4; ++c)
                P_t[(ki * 4 + c) * 68 + qi * 4 + r] = p[r][c];

        // rescale U
#pragma unroll
        for (int r = 0; r < 4; ++r)
#pragma unroll
            for (int c = 0; c < 4; ++c) U[r][c] *= alpha[r];

        __syncthreads();   // P_t visible (cheap insurance; also orders x reuse)

        // ---- PX: U[q][d] += P[q][j] * x[j][d], K=64 keys ----
#pragma unroll 8
        for (int j = 0; j < 64; ++j) {
            floatx4 a = *(const floatx4*)(P_t + j * 68 + qi * 4);
            floatx4 b = *(const floatx4*)(x_r + j * 68 + ki * 4);
#pragma unroll
            for (int r = 0; r < 4; ++r)
#pragma unroll
                for (int c = 0; c < 4; ++c) U[r][c] = fmaf(a[r], b[c], U[r][c]);
        }
    }

    // ---- write Un = U / l  (rows q0+qi*4+r, cols ki*4..+3) ----
#pragma unroll
    for (int r = 0; r < 4; ++r) {
        const float linv = 1.0f / l[r];
        floatx4 v;
#pragma unroll
        for (int c = 0; c < 4; ++c) v[c] = U[r][c] * linv;
        *(floatx4*)(Un + ((size_t)bb * S_ + q0 + qi * 4 + r) * 64 + ki * 4) = v;
    }
}

// K4: out = Un @ Wv   [32768 x 64] @ [64 x 1024] -> fp32 out (134 MB write).
// Block: 64 rows x 512 cols; thread owns cols c and c+256 (128 w-regs).
__global__ __launch_bounds__(256, 2) void k_out(
        const float* __restrict__ Un, const float* __restrict__ W,
        float* __restrict__ out) {
    __shared__ __align__(16) float us[64 * 64];
    const int tid = threadIdx.x;
    const int r0  = (blockIdx.x >> 1) * 64;
    const int cb  = (blockIdx.x & 1) * 512;
    const int c0  = cb + tid;

    float w0[64], w1[64];
#pragma unroll
    for (int d = 0; d < 64; ++d) {
        w0[d] = W[(size_t)d * 3072 + 2048 + c0];
        w1[d] = W[(size_t)d * 3072 + 2048 + c0 + 256];
    }
    {
        const floatx4* src = (const floatx4*)(Un + (size_t)r0 * 64);
        floatx4* dst = (floatx4*)us;
#pragma unroll
        for (int i = 0; i < 4; ++i) dst[tid * 4 + i] = src[tid * 4 + i];
    }
    __syncthreads();

    for (int row = 0; row < 64; ++row) {
        const floatx4* ur = (const floatx4*)(us + row * 64);
        float a0 = 0.f, a1 = 0.f;
#pragma unroll
        for (int j = 0; j < 16; ++j) {
            floatx4 u = ur[j];
            a0 = fmaf(u.x, w0[4 * j + 0], a0); a1 = fmaf(u.x, w1[4 * j + 0], a1);
            a0 = fmaf(u.y, w0[4 * j + 1], a0); a1 = fmaf(u.y, w1[4 * j + 1], a1);
            a0 = fmaf(u.z, w0[4 * j + 2], a0); a1 = fmaf(u.z, w1[4 * j + 2], a1);
            a0 = fmaf(u.w, w0[4 * j + 3], a0); a1 = fmaf(u.w, w1[4 * j + 3], a1);
        }
        float* op = out + (size_t)(r0 + row) * HD_ + c0;
        op[0]   = a0;
        op[256] = a1;
    }
}

extern "C" void kernel_launch(void* const* d_in, const int* in_sizes, int n_in,
                              void* d_out, int out_size, void* d_ws, size_t ws_size,
                              hipStream_t stream) {
    const float* x = (const float*)d_in[0];
    const float* W = (const float*)d_in[1];
    float* out = (float*)d_out;

    float* M  = (float*)d_ws;                 // 64*64
    float* y  = M + 4096;                     // 32768*64
    float* Un = y + (size_t)32768 * 64;       // 32768*64   (~16.8 MB total)

    k_M    <<<dim3(64),   64,  0, stream>>>(W, M);
    k_y    <<<dim3(256),  256, 0, stream>>>(x, M, y);
    k_attn2<<<dim3(512),  256, 0, stream>>>(x, y, Un);
    k_out  <<<dim3(1024), 256, 0, stream>>>(Un, W, out);
}